// Round 12
// baseline (29035.355 us; speedup 1.0000x reference)
//
#include <hip/hip_runtime.h>
#include <hip/hip_bf16.h>

// Sizes from the reference
#define T_   4096
#define E_   8
#define NCON 208   // consumer blocks in the mega-kernel

typedef unsigned long long ull;

__device__ __forceinline__ float sigm(float x)  { return 1.0f / (1.0f + __expf(-x)); }
__device__ __forceinline__ float tanh_(float x) { return 1.0f - 2.0f / (__expf(2.0f * x) + 1.0f); }

__device__ __forceinline__ ull aload64(const ull* p) {
  return __hip_atomic_load(p, __ATOMIC_RELAXED, __HIP_MEMORY_SCOPE_AGENT);
}
__device__ __forceinline__ int aload32(const int* p) {
  return __hip_atomic_load(p, __ATOMIC_RELAXED, __HIP_MEMORY_SCOPE_AGENT);
}
__device__ __forceinline__ float aloadf(const float* p) {
  return __hip_atomic_load(p, __ATOMIC_RELAXED, __HIP_MEMORY_SCOPE_AGENT);
}
// barrier draining LDS (lgkm) but not vector memory
__device__ __forceinline__ void lbar() {
  asm volatile("s_waitcnt lgkmcnt(0)\n\ts_barrier" ::: "memory");
}
// per-wave drain of this wave's outstanding vector-memory ops
__device__ __forceinline__ void wave_drain() {
  asm volatile("s_waitcnt vmcnt(0)" ::: "memory");
}

#define FMA_8(ACC, W, VA, VB)                                   \
  ACC[0] = fmaf((W), (VA).x, ACC[0]); ACC[1] = fmaf((W), (VA).y, ACC[1]); \
  ACC[2] = fmaf((W), (VA).z, ACC[2]); ACC[3] = fmaf((W), (VA).w, ACC[3]); \
  ACC[4] = fmaf((W), (VB).x, ACC[4]); ACC[5] = fmaf((W), (VB).y, ACC[5]); \
  ACC[6] = fmaf((W), (VB).z, ACC[6]); ACC[7] = fmaf((W), (VB).w, ACC[7]);

// ---------------------------------------------------------------------------
// initK: K-major packed weight copies + zero flag rings (now 32 lines/group)
// ---------------------------------------------------------------------------
__global__ void initK(const float* __restrict__ Wih_p0, const float* __restrict__ Whh_p0,
                      const float* __restrict__ Wih_p1, const float* __restrict__ Whh_p1,
                      const float* __restrict__ Wih_c0, const float* __restrict__ Whh_c0,
                      const float* __restrict__ Wih_c1, const float* __restrict__ Whh_c1,
                      const float* __restrict__ Wih_o,
                      float* wt_p0, float* wt_p1, float* wt_c0, float* wt_c1,
                      float* wt_o1, float* wt_o2, int* flags) {
  const int NW = 458752 + 524288 + 131072 + 131072 + 131072 + 98304;
  const int NF = 2 * 64 * 32 * 32 + 512 * 32;   // flag rings (2 waves/wg) + flagC
  const int NTOT = NW + NF;
  const int gsz = gridDim.x * blockDim.x;
  for (int i = blockIdx.x * blockDim.x + threadIdx.x; i < NTOT; i += gsz) {
    int idx = i;
    if (idx < 458752) { int k = idx >> 10, c = idx & 1023;
      int wg = c >> 6, r6 = c & 63, gate = r6 >> 4, jl = r6 & 15;
      int col = gate * 256 + wg * 16 + jl;
      wt_p0[idx] = (k < 192) ? Wih_p0[col * 192 + k] : Whh_p0[col * 256 + (k - 192)]; continue; }
    idx -= 458752;
    if (idx < 524288) { int k = idx >> 10, c = idx & 1023;
      int wg = c >> 6, r6 = c & 63, gate = r6 >> 4, jl = r6 & 15;
      int col = gate * 256 + wg * 16 + jl;
      wt_p1[idx] = (k < 256) ? Wih_p1[col * 256 + k] : Whh_p1[col * 256 + (k - 256)]; continue; }
    idx -= 524288;
    if (idx < 131072) { int k = idx >> 9, r = idx & 511;
      wt_c0[idx] = (k < 128) ? Wih_c0[r * 128 + k] : Whh_c0[r * 128 + (k - 128)]; continue; }
    idx -= 131072;
    if (idx < 131072) { int k = idx >> 9, r = idx & 511;
      wt_c1[idx] = (k < 128) ? Wih_c1[r * 128 + k] : Whh_c1[r * 128 + (k - 128)]; continue; }
    idx -= 131072;
    if (idx < 131072) { int k = idx >> 9, r = idx & 511;
      wt_o1[idx] = Wih_o[r * 448 + k]; continue; }
    idx -= 131072;
    if (idx < 98304) { int k = idx >> 9, r = idx & 511;
      wt_o2[idx] = Wih_o[r * 448 + 256 + k]; continue; }
    idx -= 98304;
    flags[idx] = 0;
  }
}

// ---------------------------------------------------------------------------
// opre2K: parallel over t. opre2[t][e][512] = Wih_o[:,256:448] @ x(t,e)  (bf16)
// ---------------------------------------------------------------------------
__global__ void opre2K(const float* __restrict__ feat, const float* __restrict__ wt_o2,
                       __hip_bfloat16* __restrict__ opre2) {
  __shared__ float xb[192 * 8];
  const int t = blockIdx.x, tid = threadIdx.x;
  const float* ft = feat + (size_t)t * 640;
  for (int idx = tid; idx < 192 * 8; idx += 256) {
    int k = idx >> 3, e = idx & 7;
    xb[idx] = (k < 128) ? ft[k] : ft[128 + e * 64 + (k - 128)];
  }
  __syncthreads();
  const int r = tid;
  float A0[8] = {0,0,0,0,0,0,0,0};
  float A1[8] = {0,0,0,0,0,0,0,0};
  const float4* x4 = (const float4*)xb;
  #pragma unroll 2
  for (int k = 0; k < 192; ++k) {
    float w0 = wt_o2[k * 512 + r];
    float w1 = wt_o2[k * 512 + 256 + r];
    float4 a = x4[k * 2], b = x4[k * 2 + 1];
    FMA_8(A0, w0, a, b);
    FMA_8(A1, w1, a, b);
  }
  #pragma unroll
  for (int e = 0; e < 8; ++e) {
    opre2[((size_t)t * 8 + e) * 512 + r]       = __float2bfloat16(A0[e]);
    opre2[((size_t)t * 8 + e) * 512 + 256 + r] = __float2bfloat16(A1[e]);
  }
}

// ---------------------------------------------------------------------------
// comm cell (unchanged math)
// ---------------------------------------------------------------------------
__device__ __forceinline__ void comm_cell(
    const float* __restrict__ wt, const float* __restrict__ bias,
    const float* xin, float* hL, float* cL, float* glb, float* hout,
    float alpha, int tid) {
  const int r = tid;
  float A0[8] = {0,0,0,0,0,0,0,0};
  float A1[8] = {0,0,0,0,0,0,0,0};
  const float4* x4 = (const float4*)xin;
  #pragma unroll 2
  for (int k = 0; k < 128; ++k) {
    float w0 = wt[k * 512 + r];
    float w1 = wt[k * 512 + 256 + r];
    float4 a = x4[k * 2], b = x4[k * 2 + 1];
    FMA_8(A0, w0, a, b);
    FMA_8(A1, w1, a, b);
  }
  const float4* h4 = (const float4*)hL;
  #pragma unroll 2
  for (int k = 0; k < 128; ++k) {
    float w0 = wt[(128 + k) * 512 + r];
    float w1 = wt[(128 + k) * 512 + 256 + r];
    float4 a = h4[k * 2], b = h4[k * 2 + 1];
    FMA_8(A0, w0, a, b);
    FMA_8(A1, w1, a, b);
  }
  {
    float4* g4 = (float4*)glb;
    g4[r * 2]             = make_float4(A0[0], A0[1], A0[2], A0[3]);
    g4[r * 2 + 1]         = make_float4(A0[4], A0[5], A0[6], A0[7]);
    g4[(256 + r) * 2]     = make_float4(A1[0], A1[1], A1[2], A1[3]);
    g4[(256 + r) * 2 + 1] = make_float4(A1[4], A1[5], A1[6], A1[7]);
  }
  __syncthreads();
  for (int idx = tid; idx < 1024; idx += 256) {
    int jj = idx >> 3, tt = idx & 7;
    float gi = glb[jj * 8 + tt]         + bias[jj];
    float gf = glb[(128 + jj) * 8 + tt] + bias[128 + jj];
    float gg = glb[(256 + jj) * 8 + tt] + bias[256 + jj];
    float go = glb[(384 + jj) * 8 + tt] + bias[384 + jj];
    float cold = cL[idx], hold = hL[idx];
    float c2 = sigm(gf) * cold + sigm(gi) * tanh_(gg);
    float h2 = sigm(go) * tanh_(c2);
    float hb = fmaf(alpha, h2 - hold, hold);
    float cb = fmaf(alpha, c2 - cold, cold);
    hL[idx] = hb; cL[idx] = cb;
    if (hout) hout[idx] = hb;
  }
  __syncthreads();
}

// ---------------------------------------------------------------------------
// MEGA kernel: 248 blocks, 256 thr, 155648 B LDS => 1 block/CU => all
// resident => flag waits deadlock-free regardless of dispatch order.
//   blocks 0-31 : phaseA. r12: per-wave flags (2/wg) remove the publish-drain
//                 barrier (3 barriers/step); busy-spin detect (no s_sleep);
//                 float2-packed LDS weights halve ds_read count.
//   blocks 32-39: phaseC per-e; blocks 40+: fused fc+comm consumers.
// ---------------------------------------------------------------------------
__launch_bounds__(256, 1)
__global__ void megaK(const float* __restrict__ feat,
                      const float* __restrict__ pre_h0, const float* __restrict__ pre_c0,
                      const float* __restrict__ wt_p0, const float* __restrict__ wt_p1,
                      const float* __restrict__ b_p0, const float* __restrict__ b_p1,
                      float* __restrict__ h0ring, float* __restrict__ h1ring,
                      float* __restrict__ h1all,
                      int* __restrict__ flagsA, int* __restrict__ flagsB,
                      const float* __restrict__ Wfc, const float* __restrict__ bfc,
                      const float* __restrict__ wt_c0, const float* __restrict__ wt_c1,
                      const float* __restrict__ b_c0, const float* __restrict__ b_c1,
                      const float* __restrict__ wt_o1, const float* __restrict__ b_o,
                      float* __restrict__ opre1, int* __restrict__ flagC,
                      const __hip_bfloat16* __restrict__ opre2,
                      const float* __restrict__ Whh_o, const float* __restrict__ out_h0,
                      const float* __restrict__ out_c0, float* __restrict__ oh_g) {
  __shared__ float lds[38912];   // 155,648 B
  const int wg = blockIdx.x, tid = threadIdx.x;
  const int r6 = tid & 63, kq = tid >> 6;
  const int uj = tid >> 3, ue = tid & 7;

  if (wg < 16) {
    // ============================ G1: layer0 ============================
    float* wl   = lds;            // 28672: weights float2-packed [k2][r6][2]
    float* xbuf = lds + 28672;    // 1536
    float* hsf  = lds + 30208;    // 2048
    float* gl   = lds + 32256;    // 2048
    for (int idx = tid; idx < 28672; idx += 256) {
      int k = idx >> 6, r = idx & 63;
      wl[(k >> 1) * 128 + r * 2 + (k & 1)] = wt_p0[(size_t)k * 1024 + wg * 64 + r];
    }
    const float2* wl2 = (const float2*)wl;
    const int j = wg * 16 + uj;
    float creg = 0.f, bi = 0.f, bff = 0.f, bg = 0.f, bo = 0.f;
    if (tid < 128) {
      creg = pre_c0[(ue * 2 + 0) * 256 + j];
      bi = b_p0[j]; bff = b_p0[256 + j]; bg = b_p0[512 + j]; bo = b_p0[768 + j];
    }
    for (int idx = tid; idx < 2048; idx += 256) {
      int k = idx >> 3, e = idx & 7;
      hsf[idx] = pre_h0[(e * 2 + 0) * 256 + k];
    }
    for (int idx = tid; idx < 1536; idx += 256) {
      int k = idx >> 3, e = idx & 7;
      xbuf[idx] = (k < 128) ? feat[k] : feat[128 + e * 64 + (k - 128)];
    }
    __syncthreads();
    float Ax[8] = {0,0,0,0,0,0,0,0};
    {
      const float4* x4 = (const float4*)xbuf;
      #pragma unroll 8
      for (int k2 = kq * 24; k2 < kq * 24 + 24; ++k2) {
        float2 w2 = wl2[k2 * 64 + r6];
        float4 a0 = x4[k2 * 4], b0 = x4[k2 * 4 + 1];
        float4 a1 = x4[k2 * 4 + 2], b1 = x4[k2 * 4 + 3];
        FMA_8(Ax, w2.x, a0, b0);
        FMA_8(Ax, w2.y, a1, b1);
      }
    }
    for (int t = 0; t < T_; ++t) {
      float px[6];
      if (t + 1 < T_) {
        const float* ft1 = feat + (size_t)(t + 1) * 640;
        #pragma unroll
        for (int i = 0; i < 6; ++i) {
          int idx = tid + i * 256; int k = idx >> 3, e = idx & 7;
          px[i] = (k < 128) ? ft1[k] : ft1[128 + e * 64 + (k - 128)];
        }
      }
      float A[8];
      #pragma unroll
      for (int i = 0; i < 8; ++i) A[i] = Ax[i];
      {  // h-part: k in [192+kq*64,+64) -> k2 in [96+kq*32,+32)
        const float4* h4 = (const float4*)hsf;
        #pragma unroll 8
        for (int k2 = 96 + kq * 32; k2 < 96 + kq * 32 + 32; ++k2) {
          float2 w2 = wl2[k2 * 64 + r6];
          int base = 4 * k2 - 384;
          float4 a0 = h4[base], b0 = h4[base + 1];
          float4 a1 = h4[base + 2], b1 = h4[base + 3];
          FMA_8(A, w2.x, a0, b0);
          FMA_8(A, w2.y, a1, b1);
        }
      }
      {
        float4* g4 = (float4*)gl;
        g4[(kq * 64 + r6) * 2]     = make_float4(A[0], A[1], A[2], A[3]);
        g4[(kq * 64 + r6) * 2 + 1] = make_float4(A[4], A[5], A[6], A[7]);
      }
      if (tid >= 224 && t >= 8) {                  // ring back-pressure (32 lines)
        const int* fp = flagsB + ((size_t)((t - 8) & 63) * 32 + (tid - 224)) * 32;
        while (aload32(fp) < t - 7) __builtin_amdgcn_s_sleep(1);
      }
      lbar();                                      // S1: gl ready
      if (tid < 128) {
        float s0 = 0.f, s1 = 0.f, s2 = 0.f, s3 = 0.f;
        #pragma unroll
        for (int q = 0; q < 4; ++q) {
          s0 += gl[q * 512 + tid];       s1 += gl[q * 512 + 128 + tid];
          s2 += gl[q * 512 + 256 + tid]; s3 += gl[q * 512 + 384 + tid];
        }
        float c2 = sigm(s1 + bff) * creg + sigm(s0 + bi) * tanh_(s2 + bg);
        float h2 = sigm(s3 + bo) * tanh_(c2);
        creg = c2;
        __hip_atomic_store(&h0ring[(size_t)(t & 7) * 2048 + wg * 128 + tid], h2,
                           __ATOMIC_RELAXED, __HIP_MEMORY_SCOPE_AGENT);
        wave_drain();                              // per-wave vmcnt(0)
        if ((tid & 63) == 0)
          __hip_atomic_store(&flagsA[((size_t)(t & 63) * 32 + wg * 2 + (tid >> 6)) * 32],
                             t + 1, __ATOMIC_RELAXED, __HIP_MEMORY_SCOPE_AGENT);
      }
      if (t + 1 >= T_) break;
      #pragma unroll
      for (int i = 0; i < 6; ++i) xbuf[tid + i * 256] = px[i];
      if (tid < 32) {                              // busy-spin detect, 32 lines
        const int* fp = flagsA + ((size_t)(t & 63) * 32 + tid) * 32;
        while (aload32(fp) < t + 1) { }
      }
      lbar();                                      // S3: xbuf ready AND published
      ull v[4];
      {
        const ull* s8 = (const ull*)(h0ring + (size_t)(t & 7) * 2048);
        #pragma unroll
        for (int i = 0; i < 4; ++i) v[i] = aload64(s8 + tid * 4 + i);
      }
      #pragma unroll
      for (int i = 0; i < 8; ++i) Ax[i] = 0.f;
      {  // x-part of t+1 (gather RTT hides under these FMAs)
        const float4* x4 = (const float4*)xbuf;
        #pragma unroll 8
        for (int k2 = kq * 24; k2 < kq * 24 + 24; ++k2) {
          float2 w2 = wl2[k2 * 64 + r6];
          float4 a0 = x4[k2 * 4], b0 = x4[k2 * 4 + 1];
          float4 a1 = x4[k2 * 4 + 2], b1 = x4[k2 * 4 + 3];
          FMA_8(Ax, w2.x, a0, b0);
          FMA_8(Ax, w2.y, a1, b1);
        }
      }
      {
        ull* d8 = (ull*)hsf;
        #pragma unroll
        for (int i = 0; i < 4; ++i) d8[tid * 4 + i] = v[i];
      }
      lbar();                                      // S4: hsf = h0(t)
    }
  } else if (wg < 32) {
    // ============================ G2: layer1 ============================
    const int wgl = wg - 16;
    float* wl  = lds;             // 32768 float2-packed
    float* xh0 = lds + 32768;     // 2048
    float* hsf = lds + 34816;     // 2048
    float* gl  = lds + 36864;     // 2048
    for (int idx = tid; idx < 32768; idx += 256) {
      int k = idx >> 6, r = idx & 63;
      wl[(k >> 1) * 128 + r * 2 + (k & 1)] = wt_p1[(size_t)k * 1024 + wgl * 64 + r];
    }
    const float2* wl2 = (const float2*)wl;
    const int j = wgl * 16 + uj;
    float creg = 0.f, bi = 0.f, bff = 0.f, bg = 0.f, bo = 0.f;
    if (tid < 128) {
      creg = pre_c0[(ue * 2 + 1) * 256 + j];
      bi = b_p1[j]; bff = b_p1[256 + j]; bg = b_p1[512 + j]; bo = b_p1[768 + j];
    }
    for (int idx = tid; idx < 2048; idx += 256) {
      int k = idx >> 3, e = idx & 7;
      hsf[idx] = pre_h0[(e * 2 + 1) * 256 + k];
    }
    __syncthreads();
    if (tid < 32) {                                // step-0 flags (32 lines)
      const int* fp = flagsA + (size_t)tid * 32;
      while (aload32(fp) < 1) __builtin_amdgcn_s_sleep(1);
    }
    __syncthreads();
    {
      const ull* s8 = (const ull*)h0ring;          // slot 0
      ull* d8 = (ull*)xh0;
      #pragma unroll
      for (int i = 0; i < 4; ++i) d8[tid * 4 + i] = aload64(s8 + tid * 4 + i);
    }
    __syncthreads();
    float Ax[8] = {0,0,0,0,0,0,0,0};
    {
      const float4* x4 = (const float4*)xh0;
      #pragma unroll 8
      for (int k2 = kq * 32; k2 < kq * 32 + 32; ++k2) {
        float2 w2 = wl2[k2 * 64 + r6];
        float4 a0 = x4[k2 * 4], b0 = x4[k2 * 4 + 1];
        float4 a1 = x4[k2 * 4 + 2], b1 = x4[k2 * 4 + 3];
        FMA_8(Ax, w2.x, a0, b0);
        FMA_8(Ax, w2.y, a1, b1);
      }
    }
    for (int t = 0; t < T_; ++t) {
      float A[8];
      #pragma unroll
      for (int i = 0; i < 8; ++i) A[i] = Ax[i];
      {  // h1-part: k2 in [128+kq*32,+32)
        const float4* h4 = (const float4*)hsf;
        #pragma unroll 8
        for (int k2 = 128 + kq * 32; k2 < 128 + kq * 32 + 32; ++k2) {
          float2 w2 = wl2[k2 * 64 + r6];
          int base = 4 * k2 - 512;
          float4 a0 = h4[base], b0 = h4[base + 1];
          float4 a1 = h4[base + 2], b1 = h4[base + 3];
          FMA_8(A, w2.x, a0, b0);
          FMA_8(A, w2.y, a1, b1);
        }
      }
      {
        float4* g4 = (float4*)gl;
        g4[(kq * 64 + r6) * 2]     = make_float4(A[0], A[1], A[2], A[3]);
        g4[(kq * 64 + r6) * 2 + 1] = make_float4(A[4], A[5], A[6], A[7]);
      }
      lbar();                                      // S1
      if (tid < 128) {
        float s0 = 0.f, s1 = 0.f, s2 = 0.f, s3 = 0.f;
        #pragma unroll
        for (int q = 0; q < 4; ++q) {
          s0 += gl[q * 512 + tid];       s1 += gl[q * 512 + 128 + tid];
          s2 += gl[q * 512 + 256 + tid]; s3 += gl[q * 512 + 384 + tid];
        }
        float c2 = sigm(s1 + bff) * creg + sigm(s0 + bi) * tanh_(s2 + bg);
        float h2 = sigm(s3 + bo) * tanh_(c2);
        creg = c2;
        __hip_atomic_store(&h1ring[(size_t)(t & 7) * 2048 + wgl * 128 + tid], h2,
                           __ATOMIC_RELAXED, __HIP_MEMORY_SCOPE_AGENT);
        __hip_atomic_store(&h1all[(size_t)t * 2048 + wgl * 128 + tid], h2,
                           __ATOMIC_RELAXED, __HIP_MEMORY_SCOPE_AGENT);
        wave_drain();                              // per-wave vmcnt(0)
        if ((tid & 63) == 0)
          __hip_atomic_store(&flagsB[((size_t)(t & 63) * 32 + wgl * 2 + (tid >> 6)) * 32],
                             t + 1, __ATOMIC_RELAXED, __HIP_MEMORY_SCOPE_AGENT);
      }
      if (t + 1 >= T_) break;
      if (tid < 64) {                              // combined busy-spin detect
        const int* fp = (tid < 32)
            ? flagsA + ((size_t)((t + 1) & 63) * 32 + tid) * 32
            : flagsB + ((size_t)(t & 63) * 32 + (tid - 32)) * 32;
        const int want = (tid < 32) ? t + 2 : t + 1;
        while (aload32(fp) < want) { }
      }
      lbar();                                      // S3: both ready
      {                                            // both gathers back-to-back
        const ull* s0p = (const ull*)(h0ring + (size_t)((t + 1) & 7) * 2048);
        const ull* s1p = (const ull*)(h1ring + (size_t)(t & 7) * 2048);
        ull v0[4], v1[4];
        #pragma unroll
        for (int i = 0; i < 4; ++i) v0[i] = aload64(s0p + tid * 4 + i);
        #pragma unroll
        for (int i = 0; i < 4; ++i) v1[i] = aload64(s1p + tid * 4 + i);
        ull* d0 = (ull*)xh0; ull* d1 = (ull*)hsf;
        #pragma unroll
        for (int i = 0; i < 4; ++i) { d0[tid * 4 + i] = v0[i]; d1[tid * 4 + i] = v1[i]; }
      }
      lbar();                                      // S4
      #pragma unroll
      for (int i = 0; i < 8; ++i) Ax[i] = 0.f;
      {  // h0-part of t+1
        const float4* x4 = (const float4*)xh0;
        #pragma unroll 8
        for (int k2 = kq * 32; k2 < kq * 32 + 32; ++k2) {
          float2 w2 = wl2[k2 * 64 + r6];
          float4 a0 = x4[k2 * 4], b0 = x4[k2 * 4 + 1];
          float4 a1 = x4[k2 * 4 + 2], b1 = x4[k2 * 4 + 3];
          FMA_8(Ax, w2.x, a0, b0);
          FMA_8(Ax, w2.y, a1, b1);
        }
      }
    }
  } else if (wg < 40) {
    // ============================ phaseC (per e) ============================
    const int e = wg - 32;
    float* wlds = lds;            // [k][256] rows 256-511
    float* ohl  = lds + 32768;    // 128
    float* gl   = lds + 32896;    // 512
    for (int idx = tid; idx < 32768; idx += 256) {
      int k = idx >> 8, rr = idx & 255;
      wlds[idx] = Whh_o[(256 + rr) * 128 + k];
    }
    float w[128];
    #pragma unroll
    for (int k = 0; k < 128; ++k) w[k] = Whh_o[tid * 128 + k];
    if (tid < 128) ohl[tid] = out_h0[e * 128 + tid];
    float creg = (tid < 128) ? out_c0[e * 128 + tid] : 0.f;
    __syncthreads();
    if (tid == 0) { while (aload32(&flagC[0]) == 0) __builtin_amdgcn_s_sleep(4); }
    __syncthreads();
    const int r0 = tid, r1 = tid + 256;
    float pa = aloadf(&opre1[r0]), pb = aloadf(&opre1[r1]);
    float qa = __bfloat162float(opre2[(size_t)e * 512 + r0]);
    float qb = __bfloat162float(opre2[(size_t)e * 512 + r1]);
    float na = aloadf(&opre1[512 + r0]), nb = aloadf(&opre1[512 + r1]);
    float ma = __bfloat162float(opre2[(size_t)(8 + e) * 512 + r0]);
    float mb = __bfloat162float(opre2[(size_t)(8 + e) * 512 + r1]);
    for (int t = 0; t < T_; ++t) {
      float a0 = pa + qa, a1 = pb + qb;
      pa = na; pb = nb; qa = ma; qb = mb;
      if ((t & 7) == 6 && t + 2 < T_) {
        if (tid == 0) { while (aload32(&flagC[((t + 2) >> 3) * 32]) == 0) __builtin_amdgcn_s_sleep(4); }
        __syncthreads();
      }
      if (t + 2 < T_) {
        na = aloadf(&opre1[(size_t)(t + 2) * 512 + r0]);
        nb = aloadf(&opre1[(size_t)(t + 2) * 512 + r1]);
        ma = __bfloat162float(opre2[((size_t)(t + 2) * 8 + e) * 512 + r0]);
        mb = __bfloat162float(opre2[((size_t)(t + 2) * 8 + e) * 512 + r1]);
      }
      const float4* o4 = (const float4*)ohl;
      #pragma unroll
      for (int kk = 0; kk < 32; ++kk) {
        float4 x = o4[kk];
        a0 = fmaf(w[kk * 4 + 0], x.x, a0); a0 = fmaf(w[kk * 4 + 1], x.y, a0);
        a0 = fmaf(w[kk * 4 + 2], x.z, a0); a0 = fmaf(w[kk * 4 + 3], x.w, a0);
        a1 = fmaf(wlds[(kk * 4 + 0) * 256 + tid], x.x, a1);
        a1 = fmaf(wlds[(kk * 4 + 1) * 256 + tid], x.y, a1);
        a1 = fmaf(wlds[(kk * 4 + 2) * 256 + tid], x.z, a1);
        a1 = fmaf(wlds[(kk * 4 + 3) * 256 + tid], x.w, a1);
      }
      gl[r0] = a0; gl[r1] = a1;
      __syncthreads();
      if (tid < 128) {
        float gi = gl[tid], gf = gl[128 + tid], gg = gl[256 + tid], go = gl[384 + tid];
        float c2 = sigm(gf) * creg + sigm(gi) * tanh_(gg);
        float h2 = sigm(go) * tanh_(c2);
        creg = c2;
        ohl[tid] = h2;
        oh_g[(size_t)t * 1024 + e * 128 + tid] = h2;
      }
      __syncthreads();
    }
  } else {
    // ==================== consumers: fused fc + comm ====================
    const int cb = wg - 40;
    float* h1c    = lds;          // 16384
    float* polAll = lds + 16384;  // 8192
    float* ch0 = lds + 24576; float* cc0 = lds + 25600;
    float* ch1 = lds + 26624; float* cc1 = lds + 27648;
    float* h0b = lds + 28672;     // 1024
    float* glb = lds + 29696;     // 4096
    for (int chunk = cb; chunk < 512; chunk += NCON) {
      const int t0 = chunk * 8;
      if (tid < 32) {
        const int* fp = flagsB + ((size_t)((t0 + 7) & 63) * 32 + tid) * 32;
        while (aload32(fp) < t0 + 8) __builtin_amdgcn_s_sleep(4);
      }
      __syncthreads();
      {
        const ull* src = (const ull*)(h1all + (size_t)t0 * 2048);
        ull* dst = (ull*)h1c;
        for (int i = tid; i < 8192; i += 256) dst[i] = aload64(src + i);
      }
      __syncthreads();
      {  // fc for 8 ts -> polAll[e][c*8+tt]
        const int c = tid >> 1, half = tid & 1;
        const float bv = bfc[c];
        const float* wrow = Wfc + c * 256;
        for (int tt = 0; tt < 8; ++tt) {
          float a0 = bv, a1 = bv, a2 = bv, a3 = bv;
          const float4* h4 = (const float4*)(h1c + tt * 2048);
          #pragma unroll 4
          for (int k = 0; k < 256; ++k) {
            float wv = wrow[k];
            float4 x = h4[k * 2 + half];
            a0 = fmaf(wv, x.x, a0); a1 = fmaf(wv, x.y, a1);
            a2 = fmaf(wv, x.z, a2); a3 = fmaf(wv, x.w, a3);
          }
          float vv[4] = {a0, a1, a2, a3};
          #pragma unroll
          for (int i = 0; i < 4; ++i) {
            float v = vv[i];
            v = (v > 0.f) ? v : 0.05f * v;
            polAll[(half * 4 + i) * 1024 + c * 8 + tt] = v;
          }
        }
      }
      for (int idx = tid; idx < 1024; idx += 256) { ch0[idx]=0.f; cc0[idx]=0.f; ch1[idx]=0.f; cc1[idx]=0.f; }
      __syncthreads();
      float alpha = 1.0f;
      for (int rd = 0; rd < 3; ++rd) {
        for (int e = 0; e < E_; ++e) {
          comm_cell(wt_c0, b_c0, polAll + e * 1024, ch0, cc0, glb, h0b, alpha, tid);
          comm_cell(wt_c1, b_c1, h0b, ch1, cc1, glb, nullptr, alpha, tid);
        }
        alpha *= 0.333f;
      }
      {  // opre1 epilogue (atomic stores)
        const int r = tid;
        float A0[8], A1[8];
        #pragma unroll
        for (int tt = 0; tt < 8; ++tt) { A0[tt] = b_o[r]; A1[tt] = b_o[256 + r]; }
        const float4* c04 = (const float4*)cc0;
        const float4* c14 = (const float4*)cc1;
        #pragma unroll 2
        for (int k = 0; k < 128; ++k) {
          float w0 = wt_o1[k * 512 + r], w1 = wt_o1[k * 512 + 256 + r];
          float4 a = c04[k * 2], b = c04[k * 2 + 1];
          FMA_8(A0, w0, a, b);
          FMA_8(A1, w1, a, b);
        }
        #pragma unroll 2
        for (int k = 0; k < 128; ++k) {
          float w0 = wt_o1[(128 + k) * 512 + r], w1 = wt_o1[(128 + k) * 512 + 256 + r];
          float4 a = c14[k * 2], b = c14[k * 2 + 1];
          FMA_8(A0, w0, a, b);
          FMA_8(A1, w1, a, b);
        }
        #pragma unroll
        for (int tt = 0; tt < 8; ++tt) {
          __hip_atomic_store(&opre1[((size_t)(t0 + tt)) * 512 + r], A0[tt],
                             __ATOMIC_RELAXED, __HIP_MEMORY_SCOPE_AGENT);
          __hip_atomic_store(&opre1[((size_t)(t0 + tt)) * 512 + 256 + r], A1[tt],
                             __ATOMIC_RELAXED, __HIP_MEMORY_SCOPE_AGENT);
        }
      }
      __syncthreads();                             // drain opre1 (vmcnt0)
      if (tid == 0)
        __hip_atomic_store(&flagC[chunk * 32], 1, __ATOMIC_RELAXED, __HIP_MEMORY_SCOPE_AGENT);
      __syncthreads();
    }
  }
}

// ---------------------------------------------------------------------------
// phaseD: parallel over t: softmaxes
// ---------------------------------------------------------------------------
__global__ void phaseD(const float* __restrict__ oh_g,
                       const float* __restrict__ Wtar, const float* __restrict__ btar,
                       const float* __restrict__ Wdir, const float* __restrict__ bdir,
                       float* __restrict__ outp) {
  __shared__ float ohl[1024];
  const int t = blockIdx.x, tid = threadIdx.x;  // 64 threads
  for (int idx = tid; idx < 1024; idx += 64) ohl[idx] = oh_g[(size_t)t * 1024 + idx];
  __syncthreads();
  const int f = tid;
  for (int e = 0; e < E_; ++e) {
    float acc = btar[f];
    const float* wr = Wtar + f * 128;
    #pragma unroll 4
    for (int k = 0; k < 128; ++k) acc = fmaf(wr[k], ohl[e * 128 + k], acc);
    float m = acc;
    #pragma unroll
    for (int off = 32; off; off >>= 1) m = fmaxf(m, __shfl_xor(m, off, 64));
    float ex = __expf(acc - m);
    float s = ex;
    #pragma unroll
    for (int off = 32; off; off >>= 1) s += __shfl_xor(s, off, 64);
    outp[((size_t)t * 8 + e) * 64 + f] = ex / s;
  }
  if (tid < 8) {
    int e = tid;
    float d0 = bdir[0], d1 = bdir[1], d2 = bdir[2];
    #pragma unroll 4
    for (int k = 0; k < 128; ++k) {
      float x = ohl[e * 128 + k];
      d0 = fmaf(Wdir[k], x, d0);
      d1 = fmaf(Wdir[128 + k], x, d1);
      d2 = fmaf(Wdir[256 + k], x, d2);
    }
    float m = fmaxf(d0, fmaxf(d1, d2));
    float x0 = __expf(d0 - m), x1 = __expf(d1 - m), x2 = __expf(d2 - m);
    float s = x0 + x1 + x2;
    float* dp = outp + (size_t)T_ * 8 * 64 + ((size_t)t * 8 + e) * 3;
    dp[0] = x0 / s; dp[1] = x1 / s; dp[2] = x2 / s;
  }
}

extern "C" void kernel_launch(void* const* d_in, const int* in_sizes, int n_in,
                              void* d_out, int out_size, void* d_ws, size_t ws_size,
                              hipStream_t stream) {
  (void)in_sizes; (void)n_in; (void)out_size; (void)ws_size;
  const float* feat   = (const float*)d_in[0];
  const float* pre_h0 = (const float*)d_in[1];
  const float* pre_c0 = (const float*)d_in[2];
  const float* out_h0 = (const float*)d_in[3];
  const float* out_c0 = (const float*)d_in[4];
  const float* Wih_p0 = (const float*)d_in[5];
  const float* Whh_p0 = (const float*)d_in[6];
  const float* b_p0   = (const float*)d_in[7];
  const float* Wih_p1 = (const float*)d_in[8];
  const float* Whh_p1 = (const float*)d_in[9];
  const float* b_p1   = (const float*)d_in[10];
  const float* Wfc    = (const float*)d_in[11];
  const float* bfc    = (const float*)d_in[12];
  const float* Wih_c0 = (const float*)d_in[13];
  const float* Whh_c0 = (const float*)d_in[14];
  const float* b_c0   = (const float*)d_in[15];
  const float* Wih_c1 = (const float*)d_in[16];
  const float* Whh_c1 = (const float*)d_in[17];
  const float* b_c1   = (const float*)d_in[18];
  const float* Wih_o  = (const float*)d_in[19];
  const float* Whh_o  = (const float*)d_in[20];
  const float* b_o    = (const float*)d_in[21];
  const float* Wtar   = (const float*)d_in[22];
  const float* btar   = (const float*)d_in[23];
  const float* Wdir   = (const float*)d_in[24];
  const float* bdir   = (const float*)d_in[25];
  float* outp = (float*)d_out;

  float* ws = (float*)d_ws;
  size_t off = 0;
  float* opre1    = ws + off; off += (size_t)T_ * 512;
  float* oh_g     = ws + off; off += (size_t)T_ * E_ * 128;
  float* wt_p0    = ws + off; off += (size_t)448 * 1024;
  float* wt_p1    = ws + off; off += (size_t)512 * 1024;
  float* wt_c0    = ws + off; off += (size_t)256 * 512;
  float* wt_c1    = ws + off; off += (size_t)256 * 512;
  float* wt_o1    = ws + off; off += (size_t)256 * 512;
  float* wt_o2    = ws + off; off += (size_t)192 * 512;
  __hip_bfloat16* opre2 = (__hip_bfloat16*)(ws + off);
  off += (size_t)T_ * E_ * 512 / 2;
  float* h1all  = ws + off; off += (size_t)T_ * 2048;
  float* h0ring = ws + off; off += (size_t)8 * 2048;
  float* h1ring = ws + off; off += (size_t)8 * 2048;
  int* flags    = (int*)(ws + off);          // flagsA(64*32*32) + flagsB + flagC
  int* flagsA   = flags;
  int* flagsB   = flags + (size_t)64 * 32 * 32;
  int* flagC    = flags + (size_t)2 * 64 * 32 * 32;   // 512 slots x 32 stride

  initK<<<dim3(1024), dim3(256), 0, stream>>>(
      Wih_p0, Whh_p0, Wih_p1, Whh_p1, Wih_c0, Whh_c0, Wih_c1, Whh_c1, Wih_o,
      wt_p0, wt_p1, wt_c0, wt_c1, wt_o1, wt_o2, flags);
  opre2K<<<dim3(T_), dim3(256), 0, stream>>>(feat, wt_o2, opre2);
  megaK<<<dim3(32 + 8 + NCON), dim3(256), 0, stream>>>(
      feat, pre_h0, pre_c0, wt_p0, wt_p1, b_p0, b_p1,
      h0ring, h1ring, h1all, flagsA, flagsB,
      Wfc, bfc, wt_c0, wt_c1, b_c0, b_c1, wt_o1, b_o, opre1, flagC,
      opre2, Whh_o, out_h0, out_c0, oh_g);
  phaseD<<<dim3(T_), dim3(64), 0, stream>>>(oh_g, Wtar, btar, Wdir, bdir, outp);
}

// Round 13
// 23741.422 us; speedup vs baseline: 1.2230x; 1.2230x over previous
//
#include <hip/hip_runtime.h>
#include <hip/hip_bf16.h>

// Sizes from the reference
#define T_   4096
#define E_   8
#define NCON 208   // consumer blocks in the mega-kernel

typedef unsigned long long ull;

__device__ __forceinline__ float sigm(float x)  { return 1.0f / (1.0f + __expf(-x)); }
__device__ __forceinline__ float tanh_(float x) { return 1.0f - 2.0f / (__expf(2.0f * x) + 1.0f); }

__device__ __forceinline__ ull aload64(const ull* p) {
  return __hip_atomic_load(p, __ATOMIC_RELAXED, __HIP_MEMORY_SCOPE_AGENT);
}
__device__ __forceinline__ int aload32(const int* p) {
  return __hip_atomic_load(p, __ATOMIC_RELAXED, __HIP_MEMORY_SCOPE_AGENT);
}
__device__ __forceinline__ float aloadf(const float* p) {
  return __hip_atomic_load(p, __ATOMIC_RELAXED, __HIP_MEMORY_SCOPE_AGENT);
}
// barrier draining LDS (lgkm) but not vector memory
__device__ __forceinline__ void lbar() {
  asm volatile("s_waitcnt lgkmcnt(0)\n\ts_barrier" ::: "memory");
}

#define FMA_8(ACC, W, VA, VB)                                   \
  ACC[0] = fmaf((W), (VA).x, ACC[0]); ACC[1] = fmaf((W), (VA).y, ACC[1]); \
  ACC[2] = fmaf((W), (VA).z, ACC[2]); ACC[3] = fmaf((W), (VA).w, ACC[3]); \
  ACC[4] = fmaf((W), (VB).x, ACC[4]); ACC[5] = fmaf((W), (VB).y, ACC[5]); \
  ACC[6] = fmaf((W), (VB).z, ACC[6]); ACC[7] = fmaf((W), (VB).w, ACC[7]);

// ---------------------------------------------------------------------------
// initK: K-major packed weight copies + zero flag rings and flagC.
// ---------------------------------------------------------------------------
__global__ void initK(const float* __restrict__ Wih_p0, const float* __restrict__ Whh_p0,
                      const float* __restrict__ Wih_p1, const float* __restrict__ Whh_p1,
                      const float* __restrict__ Wih_c0, const float* __restrict__ Whh_c0,
                      const float* __restrict__ Wih_c1, const float* __restrict__ Whh_c1,
                      const float* __restrict__ Wih_o,
                      float* wt_p0, float* wt_p1, float* wt_c0, float* wt_c1,
                      float* wt_o1, float* wt_o2, int* flags) {
  const int NW = 458752 + 524288 + 131072 + 131072 + 131072 + 98304;
  const int NF = 2 * 64 * 16 * 32 + 512 * 32;   // flag rings + flagC
  const int NTOT = NW + NF;
  const int gsz = gridDim.x * blockDim.x;
  for (int i = blockIdx.x * blockDim.x + threadIdx.x; i < NTOT; i += gsz) {
    int idx = i;
    if (idx < 458752) { int k = idx >> 10, c = idx & 1023;
      int wg = c >> 6, r6 = c & 63, gate = r6 >> 4, jl = r6 & 15;
      int col = gate * 256 + wg * 16 + jl;
      wt_p0[idx] = (k < 192) ? Wih_p0[col * 192 + k] : Whh_p0[col * 256 + (k - 192)]; continue; }
    idx -= 458752;
    if (idx < 524288) { int k = idx >> 10, c = idx & 1023;
      int wg = c >> 6, r6 = c & 63, gate = r6 >> 4, jl = r6 & 15;
      int col = gate * 256 + wg * 16 + jl;
      wt_p1[idx] = (k < 256) ? Wih_p1[col * 256 + k] : Whh_p1[col * 256 + (k - 256)]; continue; }
    idx -= 524288;
    if (idx < 131072) { int k = idx >> 9, r = idx & 511;
      wt_c0[idx] = (k < 128) ? Wih_c0[r * 128 + k] : Whh_c0[r * 128 + (k - 128)]; continue; }
    idx -= 131072;
    if (idx < 131072) { int k = idx >> 9, r = idx & 511;
      wt_c1[idx] = (k < 128) ? Wih_c1[r * 128 + k] : Whh_c1[r * 128 + (k - 128)]; continue; }
    idx -= 131072;
    if (idx < 131072) { int k = idx >> 9, r = idx & 511;
      wt_o1[idx] = Wih_o[r * 448 + k]; continue; }
    idx -= 131072;
    if (idx < 98304) { int k = idx >> 9, r = idx & 511;
      wt_o2[idx] = Wih_o[r * 448 + 256 + k]; continue; }
    idx -= 98304;
    flags[idx] = 0;
  }
}

// ---------------------------------------------------------------------------
// opre2K: parallel over t. opre2[t][e][512] = Wih_o[:,256:448] @ x(t,e)  (bf16)
// ---------------------------------------------------------------------------
__global__ void opre2K(const float* __restrict__ feat, const float* __restrict__ wt_o2,
                       __hip_bfloat16* __restrict__ opre2) {
  __shared__ float xb[192 * 8];
  const int t = blockIdx.x, tid = threadIdx.x;
  const float* ft = feat + (size_t)t * 640;
  for (int idx = tid; idx < 192 * 8; idx += 256) {
    int k = idx >> 3, e = idx & 7;
    xb[idx] = (k < 128) ? ft[k] : ft[128 + e * 64 + (k - 128)];
  }
  __syncthreads();
  const int r = tid;
  float A0[8] = {0,0,0,0,0,0,0,0};
  float A1[8] = {0,0,0,0,0,0,0,0};
  const float4* x4 = (const float4*)xb;
  #pragma unroll 2
  for (int k = 0; k < 192; ++k) {
    float w0 = wt_o2[k * 512 + r];
    float w1 = wt_o2[k * 512 + 256 + r];
    float4 a = x4[k * 2], b = x4[k * 2 + 1];
    FMA_8(A0, w0, a, b);
    FMA_8(A1, w1, a, b);
  }
  #pragma unroll
  for (int e = 0; e < 8; ++e) {
    opre2[((size_t)t * 8 + e) * 512 + r]       = __float2bfloat16(A0[e]);
    opre2[((size_t)t * 8 + e) * 512 + 256 + r] = __float2bfloat16(A1[e]);
  }
}

// ---------------------------------------------------------------------------
// comm cell (unchanged math)
// ---------------------------------------------------------------------------
__device__ __forceinline__ void comm_cell(
    const float* __restrict__ wt, const float* __restrict__ bias,
    const float* xin, float* hL, float* cL, float* glb, float* hout,
    float alpha, int tid) {
  const int r = tid;
  float A0[8] = {0,0,0,0,0,0,0,0};
  float A1[8] = {0,0,0,0,0,0,0,0};
  const float4* x4 = (const float4*)xin;
  #pragma unroll 2
  for (int k = 0; k < 128; ++k) {
    float w0 = wt[k * 512 + r];
    float w1 = wt[k * 512 + 256 + r];
    float4 a = x4[k * 2], b = x4[k * 2 + 1];
    FMA_8(A0, w0, a, b);
    FMA_8(A1, w1, a, b);
  }
  const float4* h4 = (const float4*)hL;
  #pragma unroll 2
  for (int k = 0; k < 128; ++k) {
    float w0 = wt[(128 + k) * 512 + r];
    float w1 = wt[(128 + k) * 512 + 256 + r];
    float4 a = h4[k * 2], b = h4[k * 2 + 1];
    FMA_8(A0, w0, a, b);
    FMA_8(A1, w1, a, b);
  }
  {
    float4* g4 = (float4*)glb;
    g4[r * 2]             = make_float4(A0[0], A0[1], A0[2], A0[3]);
    g4[r * 2 + 1]         = make_float4(A0[4], A0[5], A0[6], A0[7]);
    g4[(256 + r) * 2]     = make_float4(A1[0], A1[1], A1[2], A1[3]);
    g4[(256 + r) * 2 + 1] = make_float4(A1[4], A1[5], A1[6], A1[7]);
  }
  __syncthreads();
  for (int idx = tid; idx < 1024; idx += 256) {
    int jj = idx >> 3, tt = idx & 7;
    float gi = glb[jj * 8 + tt]         + bias[jj];
    float gf = glb[(128 + jj) * 8 + tt] + bias[128 + jj];
    float gg = glb[(256 + jj) * 8 + tt] + bias[256 + jj];
    float go = glb[(384 + jj) * 8 + tt] + bias[384 + jj];
    float cold = cL[idx], hold = hL[idx];
    float c2 = sigm(gf) * cold + sigm(gi) * tanh_(gg);
    float h2 = sigm(go) * tanh_(c2);
    float hb = fmaf(alpha, h2 - hold, hold);
    float cb = fmaf(alpha, c2 - cold, cold);
    hL[idx] = hb; cL[idx] = cb;
    if (hout) hout[idx] = hb;
  }
  __syncthreads();
}

// ---------------------------------------------------------------------------
// MEGA kernel (r11 configuration — measured optimum): 248 blocks, 256 thr,
// 155648 B LDS => 1 block/CU => all resident => flag waits deadlock-free.
//   blocks 0-31 : phaseA (LDS b32 weights, flag-per-WG lines, s_sleep polls)
//   blocks 32-39: phaseC per-e; blocks 40+: fused fc+comm consumers.
// r12's per-wave flags / busy-spin / float2 weights all REVERTED (measured
// regression: polling congestion + 4-way b64 LDS bank aliasing).
// ---------------------------------------------------------------------------
__launch_bounds__(256, 1)
__global__ void megaK(const float* __restrict__ feat,
                      const float* __restrict__ pre_h0, const float* __restrict__ pre_c0,
                      const float* __restrict__ wt_p0, const float* __restrict__ wt_p1,
                      const float* __restrict__ b_p0, const float* __restrict__ b_p1,
                      float* __restrict__ h0ring, float* __restrict__ h1ring,
                      float* __restrict__ h1all,
                      int* __restrict__ flagsA, int* __restrict__ flagsB,
                      const float* __restrict__ Wfc, const float* __restrict__ bfc,
                      const float* __restrict__ wt_c0, const float* __restrict__ wt_c1,
                      const float* __restrict__ b_c0, const float* __restrict__ b_c1,
                      const float* __restrict__ wt_o1, const float* __restrict__ b_o,
                      float* __restrict__ opre1, int* __restrict__ flagC,
                      const __hip_bfloat16* __restrict__ opre2,
                      const float* __restrict__ Whh_o, const float* __restrict__ out_h0,
                      const float* __restrict__ out_c0, float* __restrict__ oh_g) {
  __shared__ float lds[38912];   // 155,648 B
  const int wg = blockIdx.x, tid = threadIdx.x;
  const int r6 = tid & 63, kq = tid >> 6;
  const int uj = tid >> 3, ue = tid & 7;

  if (wg < 16) {
    // ============================ G1: layer0 ============================
    float* wl   = lds;            // 28672: weights [k][64], k<448
    float* xbuf = lds + 28672;    // 1536
    float* hsf  = lds + 30208;    // 2048
    float* gl   = lds + 32256;    // 2048
    for (int idx = tid; idx < 28672; idx += 256)
      wl[idx] = wt_p0[(size_t)(idx >> 6) * 1024 + wg * 64 + (idx & 63)];
    const int j = wg * 16 + uj;
    float creg = 0.f, bi = 0.f, bff = 0.f, bg = 0.f, bo = 0.f;
    if (tid < 128) {
      creg = pre_c0[(ue * 2 + 0) * 256 + j];
      bi = b_p0[j]; bff = b_p0[256 + j]; bg = b_p0[512 + j]; bo = b_p0[768 + j];
    }
    for (int idx = tid; idx < 2048; idx += 256) {
      int k = idx >> 3, e = idx & 7;
      hsf[idx] = pre_h0[(e * 2 + 0) * 256 + k];
    }
    for (int idx = tid; idx < 1536; idx += 256) {
      int k = idx >> 3, e = idx & 7;
      xbuf[idx] = (k < 128) ? feat[k] : feat[128 + e * 64 + (k - 128)];
    }
    __syncthreads();
    float Ax[8] = {0,0,0,0,0,0,0,0};
    {
      const float4* x4 = (const float4*)xbuf;
      #pragma unroll 8
      for (int k = kq * 48; k < kq * 48 + 48; ++k) {
        float w = wl[k * 64 + r6];
        float4 a = x4[k * 2], b = x4[k * 2 + 1];
        FMA_8(Ax, w, a, b);
      }
    }
    for (int t = 0; t < T_; ++t) {
      float px[6];
      if (t + 1 < T_) {
        const float* ft1 = feat + (size_t)(t + 1) * 640;
        #pragma unroll
        for (int i = 0; i < 6; ++i) {
          int idx = tid + i * 256; int k = idx >> 3, e = idx & 7;
          px[i] = (k < 128) ? ft1[k] : ft1[128 + e * 64 + (k - 128)];
        }
      }
      float A[8];
      #pragma unroll
      for (int i = 0; i < 8; ++i) A[i] = Ax[i];
      {
        const float4* h4 = (const float4*)hsf;
        const int kb = 192 + kq * 64;
        #pragma unroll 8
        for (int k = kb; k < kb + 64; ++k) {
          float w = wl[k * 64 + r6];
          int kk = k - 192;
          float4 a = h4[kk * 2], b = h4[kk * 2 + 1];
          FMA_8(A, w, a, b);
        }
      }
      {
        float4* g4 = (float4*)gl;
        g4[(kq * 64 + r6) * 2]     = make_float4(A[0], A[1], A[2], A[3]);
        g4[(kq * 64 + r6) * 2 + 1] = make_float4(A[4], A[5], A[6], A[7]);
      }
      if (tid >= 240 && t >= 8) {                  // ring back-pressure
        const int* fp = flagsB + ((size_t)((t - 8) & 63) * 16 + (tid - 240)) * 32;
        while (aload32(fp) < t - 7) __builtin_amdgcn_s_sleep(1);
      }
      lbar();                                      // S1
      if (tid < 128) {
        float s0 = 0.f, s1 = 0.f, s2 = 0.f, s3 = 0.f;
        #pragma unroll
        for (int q = 0; q < 4; ++q) {
          s0 += gl[q * 512 + tid];       s1 += gl[q * 512 + 128 + tid];
          s2 += gl[q * 512 + 256 + tid]; s3 += gl[q * 512 + 384 + tid];
        }
        float c2 = sigm(s1 + bff) * creg + sigm(s0 + bi) * tanh_(s2 + bg);
        float h2 = sigm(s3 + bo) * tanh_(c2);
        creg = c2;
        __hip_atomic_store(&h0ring[(size_t)(t & 7) * 2048 + wg * 128 + tid], h2,
                           __ATOMIC_RELAXED, __HIP_MEMORY_SCOPE_AGENT);
      }
      __syncthreads();                             // S2: publish drained
      if (tid == 0)
        __hip_atomic_store(&flagsA[((size_t)(t & 63) * 16 + wg) * 32], t + 1,
                           __ATOMIC_RELAXED, __HIP_MEMORY_SCOPE_AGENT);
      if (t + 1 >= T_) break;
      #pragma unroll
      for (int i = 0; i < 6; ++i) xbuf[tid + i * 256] = px[i];
      if (tid < 16) {                              // detect overlaps refill
        const int* fp = flagsA + ((size_t)(t & 63) * 16 + tid) * 32;
        while (aload32(fp) < t + 1) __builtin_amdgcn_s_sleep(1);
      }
      lbar();                                      // S3
      ull v[4];
      {
        const ull* s8 = (const ull*)(h0ring + (size_t)(t & 7) * 2048);
        #pragma unroll
        for (int i = 0; i < 4; ++i) v[i] = aload64(s8 + tid * 4 + i);
      }
      #pragma unroll
      for (int i = 0; i < 8; ++i) Ax[i] = 0.f;
      {
        const float4* x4 = (const float4*)xbuf;
        #pragma unroll 8
        for (int k = kq * 48; k < kq * 48 + 48; ++k) {
          float w = wl[k * 64 + r6];
          float4 a = x4[k * 2], b = x4[k * 2 + 1];
          FMA_8(Ax, w, a, b);
        }
      }
      {
        ull* d8 = (ull*)hsf;
        #pragma unroll
        for (int i = 0; i < 4; ++i) d8[tid * 4 + i] = v[i];
      }
      lbar();                                      // S4
    }
  } else if (wg < 32) {
    // ============================ G2: layer1 ============================
    const int wgl = wg - 16;
    float* wl  = lds;             // 32768
    float* xh0 = lds + 32768;     // 2048
    float* hsf = lds + 34816;     // 2048
    float* gl  = lds + 36864;     // 2048
    for (int idx = tid; idx < 32768; idx += 256)
      wl[idx] = wt_p1[(size_t)(idx >> 6) * 1024 + wgl * 64 + (idx & 63)];
    const int j = wgl * 16 + uj;
    float creg = 0.f, bi = 0.f, bff = 0.f, bg = 0.f, bo = 0.f;
    if (tid < 128) {
      creg = pre_c0[(ue * 2 + 1) * 256 + j];
      bi = b_p1[j]; bff = b_p1[256 + j]; bg = b_p1[512 + j]; bo = b_p1[768 + j];
    }
    for (int idx = tid; idx < 2048; idx += 256) {
      int k = idx >> 3, e = idx & 7;
      hsf[idx] = pre_h0[(e * 2 + 1) * 256 + k];
    }
    __syncthreads();
    if (tid < 16) {
      const int* fp = flagsA + (size_t)tid * 32;
      while (aload32(fp) < 1) __builtin_amdgcn_s_sleep(1);
    }
    __syncthreads();
    {
      const ull* s8 = (const ull*)h0ring;
      ull* d8 = (ull*)xh0;
      #pragma unroll
      for (int i = 0; i < 4; ++i) d8[tid * 4 + i] = aload64(s8 + tid * 4 + i);
    }
    __syncthreads();
    float Ax[8] = {0,0,0,0,0,0,0,0};
    {
      const float4* x4 = (const float4*)xh0;
      #pragma unroll 8
      for (int k = kq * 64; k < kq * 64 + 64; ++k) {
        float w = wl[k * 64 + r6];
        float4 a = x4[k * 2], b = x4[k * 2 + 1];
        FMA_8(Ax, w, a, b);
      }
    }
    for (int t = 0; t < T_; ++t) {
      float A[8];
      #pragma unroll
      for (int i = 0; i < 8; ++i) A[i] = Ax[i];
      {
        const float4* h4 = (const float4*)hsf;
        const int kb = 256 + kq * 64;
        #pragma unroll 8
        for (int k = kb; k < kb + 64; ++k) {
          float w = wl[k * 64 + r6];
          int kk = k - 256;
          float4 a = h4[kk * 2], b = h4[kk * 2 + 1];
          FMA_8(A, w, a, b);
        }
      }
      {
        float4* g4 = (float4*)gl;
        g4[(kq * 64 + r6) * 2]     = make_float4(A[0], A[1], A[2], A[3]);
        g4[(kq * 64 + r6) * 2 + 1] = make_float4(A[4], A[5], A[6], A[7]);
      }
      lbar();                                      // S1
      if (tid < 128) {
        float s0 = 0.f, s1 = 0.f, s2 = 0.f, s3 = 0.f;
        #pragma unroll
        for (int q = 0; q < 4; ++q) {
          s0 += gl[q * 512 + tid];       s1 += gl[q * 512 + 128 + tid];
          s2 += gl[q * 512 + 256 + tid]; s3 += gl[q * 512 + 384 + tid];
        }
        float c2 = sigm(s1 + bff) * creg + sigm(s0 + bi) * tanh_(s2 + bg);
        float h2 = sigm(s3 + bo) * tanh_(c2);
        creg = c2;
        __hip_atomic_store(&h1ring[(size_t)(t & 7) * 2048 + wgl * 128 + tid], h2,
                           __ATOMIC_RELAXED, __HIP_MEMORY_SCOPE_AGENT);
        __hip_atomic_store(&h1all[(size_t)t * 2048 + wgl * 128 + tid], h2,
                           __ATOMIC_RELAXED, __HIP_MEMORY_SCOPE_AGENT);
      }
      __syncthreads();                             // S2: publish drained
      if (tid == 0)
        __hip_atomic_store(&flagsB[((size_t)(t & 63) * 16 + wgl) * 32], t + 1,
                           __ATOMIC_RELAXED, __HIP_MEMORY_SCOPE_AGENT);
      if (t + 1 >= T_) break;
      if (tid < 32) {                              // combined detect
        const int* fp = (tid < 16)
            ? flagsA + ((size_t)((t + 1) & 63) * 16 + tid) * 32
            : flagsB + ((size_t)(t & 63) * 16 + (tid - 16)) * 32;
        const int want = (tid < 16) ? t + 2 : t + 1;
        while (aload32(fp) < want) __builtin_amdgcn_s_sleep(1);
      }
      lbar();                                      // S3
      {
        const ull* s0p = (const ull*)(h0ring + (size_t)((t + 1) & 7) * 2048);
        const ull* s1p = (const ull*)(h1ring + (size_t)(t & 7) * 2048);
        ull v0[4], v1[4];
        #pragma unroll
        for (int i = 0; i < 4; ++i) v0[i] = aload64(s0p + tid * 4 + i);
        #pragma unroll
        for (int i = 0; i < 4; ++i) v1[i] = aload64(s1p + tid * 4 + i);
        ull* d0 = (ull*)xh0; ull* d1 = (ull*)hsf;
        #pragma unroll
        for (int i = 0; i < 4; ++i) { d0[tid * 4 + i] = v0[i]; d1[tid * 4 + i] = v1[i]; }
      }
      lbar();                                      // S4
      #pragma unroll
      for (int i = 0; i < 8; ++i) Ax[i] = 0.f;
      {
        const float4* x4 = (const float4*)xh0;
        #pragma unroll 8
        for (int k = kq * 64; k < kq * 64 + 64; ++k) {
          float w = wl[k * 64 + r6];
          float4 a = x4[k * 2], b = x4[k * 2 + 1];
          FMA_8(Ax, w, a, b);
        }
      }
    }
  } else if (wg < 40) {
    // ============================ phaseC (per e) ============================
    const int e = wg - 32;
    float* wlds = lds;            // [k][256] rows 256-511
    float* ohl  = lds + 32768;    // 128
    float* gl   = lds + 32896;    // 512
    for (int idx = tid; idx < 32768; idx += 256) {
      int k = idx >> 8, rr = idx & 255;
      wlds[idx] = Whh_o[(256 + rr) * 128 + k];
    }
    float w[128];
    #pragma unroll
    for (int k = 0; k < 128; ++k) w[k] = Whh_o[tid * 128 + k];
    if (tid < 128) ohl[tid] = out_h0[e * 128 + tid];
    float creg = (tid < 128) ? out_c0[e * 128 + tid] : 0.f;
    __syncthreads();
    if (tid == 0) { while (aload32(&flagC[0]) == 0) __builtin_amdgcn_s_sleep(4); }
    __syncthreads();
    const int r0 = tid, r1 = tid + 256;
    float pa = aloadf(&opre1[r0]), pb = aloadf(&opre1[r1]);
    float qa = __bfloat162float(opre2[(size_t)e * 512 + r0]);
    float qb = __bfloat162float(opre2[(size_t)e * 512 + r1]);
    float na = aloadf(&opre1[512 + r0]), nb = aloadf(&opre1[512 + r1]);
    float ma = __bfloat162float(opre2[(size_t)(8 + e) * 512 + r0]);
    float mb = __bfloat162float(opre2[(size_t)(8 + e) * 512 + r1]);
    for (int t = 0; t < T_; ++t) {
      float a0 = pa + qa, a1 = pb + qb;
      pa = na; pb = nb; qa = ma; qb = mb;
      if ((t & 7) == 6 && t + 2 < T_) {
        if (tid == 0) { while (aload32(&flagC[((t + 2) >> 3) * 32]) == 0) __builtin_amdgcn_s_sleep(4); }
        __syncthreads();
      }
      if (t + 2 < T_) {
        na = aloadf(&opre1[(size_t)(t + 2) * 512 + r0]);
        nb = aloadf(&opre1[(size_t)(t + 2) * 512 + r1]);
        ma = __bfloat162float(opre2[((size_t)(t + 2) * 8 + e) * 512 + r0]);
        mb = __bfloat162float(opre2[((size_t)(t + 2) * 8 + e) * 512 + r1]);
      }
      const float4* o4 = (const float4*)ohl;
      #pragma unroll
      for (int kk = 0; kk < 32; ++kk) {
        float4 x = o4[kk];
        a0 = fmaf(w[kk * 4 + 0], x.x, a0); a0 = fmaf(w[kk * 4 + 1], x.y, a0);
        a0 = fmaf(w[kk * 4 + 2], x.z, a0); a0 = fmaf(w[kk * 4 + 3], x.w, a0);
        a1 = fmaf(wlds[(kk * 4 + 0) * 256 + tid], x.x, a1);
        a1 = fmaf(wlds[(kk * 4 + 1) * 256 + tid], x.y, a1);
        a1 = fmaf(wlds[(kk * 4 + 2) * 256 + tid], x.z, a1);
        a1 = fmaf(wlds[(kk * 4 + 3) * 256 + tid], x.w, a1);
      }
      gl[r0] = a0; gl[r1] = a1;
      __syncthreads();
      if (tid < 128) {
        float gi = gl[tid], gf = gl[128 + tid], gg = gl[256 + tid], go = gl[384 + tid];
        float c2 = sigm(gf) * creg + sigm(gi) * tanh_(gg);
        float h2 = sigm(go) * tanh_(c2);
        creg = c2;
        ohl[tid] = h2;
        oh_g[(size_t)t * 1024 + e * 128 + tid] = h2;
      }
      __syncthreads();
    }
  } else {
    // ==================== consumers: fused fc + comm ====================
    const int cb = wg - 40;
    float* h1c    = lds;          // 16384
    float* polAll = lds + 16384;  // 8192
    float* ch0 = lds + 24576; float* cc0 = lds + 25600;
    float* ch1 = lds + 26624; float* cc1 = lds + 27648;
    float* h0b = lds + 28672;     // 1024
    float* glb = lds + 29696;     // 4096
    for (int chunk = cb; chunk < 512; chunk += NCON) {
      const int t0 = chunk * 8;
      if (tid < 16) {
        const int* fp = flagsB + ((size_t)((t0 + 7) & 63) * 16 + tid) * 32;
        while (aload32(fp) < t0 + 8) __builtin_amdgcn_s_sleep(4);
      }
      __syncthreads();
      {
        const ull* src = (const ull*)(h1all + (size_t)t0 * 2048);
        ull* dst = (ull*)h1c;
        for (int i = tid; i < 8192; i += 256) dst[i] = aload64(src + i);
      }
      __syncthreads();
      {  // fc for 8 ts -> polAll[e][c*8+tt]
        const int c = tid >> 1, half = tid & 1;
        const float bv = bfc[c];
        const float* wrow = Wfc + c * 256;
        for (int tt = 0; tt < 8; ++tt) {
          float a0 = bv, a1 = bv, a2 = bv, a3 = bv;
          const float4* h4 = (const float4*)(h1c + tt * 2048);
          #pragma unroll 4
          for (int k = 0; k < 256; ++k) {
            float wv = wrow[k];
            float4 x = h4[k * 2 + half];
            a0 = fmaf(wv, x.x, a0); a1 = fmaf(wv, x.y, a1);
            a2 = fmaf(wv, x.z, a2); a3 = fmaf(wv, x.w, a3);
          }
          float vv[4] = {a0, a1, a2, a3};
          #pragma unroll
          for (int i = 0; i < 4; ++i) {
            float v = vv[i];
            v = (v > 0.f) ? v : 0.05f * v;
            polAll[(half * 4 + i) * 1024 + c * 8 + tt] = v;
          }
        }
      }
      for (int idx = tid; idx < 1024; idx += 256) { ch0[idx]=0.f; cc0[idx]=0.f; ch1[idx]=0.f; cc1[idx]=0.f; }
      __syncthreads();
      float alpha = 1.0f;
      for (int rd = 0; rd < 3; ++rd) {
        for (int e = 0; e < E_; ++e) {
          comm_cell(wt_c0, b_c0, polAll + e * 1024, ch0, cc0, glb, h0b, alpha, tid);
          comm_cell(wt_c1, b_c1, h0b, ch1, cc1, glb, nullptr, alpha, tid);
        }
        alpha *= 0.333f;
      }
      {  // opre1 epilogue (atomic stores)
        const int r = tid;
        float A0[8], A1[8];
        #pragma unroll
        for (int tt = 0; tt < 8; ++tt) { A0[tt] = b_o[r]; A1[tt] = b_o[256 + r]; }
        const float4* c04 = (const float4*)cc0;
        const float4* c14 = (const float4*)cc1;
        #pragma unroll 2
        for (int k = 0; k < 128; ++k) {
          float w0 = wt_o1[k * 512 + r], w1 = wt_o1[k * 512 + 256 + r];
          float4 a = c04[k * 2], b = c04[k * 2 + 1];
          FMA_8(A0, w0, a, b);
          FMA_8(A1, w1, a, b);
        }
        #pragma unroll 2
        for (int k = 0; k < 128; ++k) {
          float w0 = wt_o1[(128 + k) * 512 + r], w1 = wt_o1[(128 + k) * 512 + 256 + r];
          float4 a = c14[k * 2], b = c14[k * 2 + 1];
          FMA_8(A0, w0, a, b);
          FMA_8(A1, w1, a, b);
        }
        #pragma unroll
        for (int tt = 0; tt < 8; ++tt) {
          __hip_atomic_store(&opre1[((size_t)(t0 + tt)) * 512 + r], A0[tt],
                             __ATOMIC_RELAXED, __HIP_MEMORY_SCOPE_AGENT);
          __hip_atomic_store(&opre1[((size_t)(t0 + tt)) * 512 + 256 + r], A1[tt],
                             __ATOMIC_RELAXED, __HIP_MEMORY_SCOPE_AGENT);
        }
      }
      __syncthreads();                             // drain opre1 (vmcnt0)
      if (tid == 0)
        __hip_atomic_store(&flagC[chunk * 32], 1, __ATOMIC_RELAXED, __HIP_MEMORY_SCOPE_AGENT);
      __syncthreads();
    }
  }
}

// ---------------------------------------------------------------------------
// phaseD: parallel over t: softmaxes
// ---------------------------------------------------------------------------
__global__ void phaseD(const float* __restrict__ oh_g,
                       const float* __restrict__ Wtar, const float* __restrict__ btar,
                       const float* __restrict__ Wdir, const float* __restrict__ bdir,
                       float* __restrict__ outp) {
  __shared__ float ohl[1024];
  const int t = blockIdx.x, tid = threadIdx.x;  // 64 threads
  for (int idx = tid; idx < 1024; idx += 64) ohl[idx] = oh_g[(size_t)t * 1024 + idx];
  __syncthreads();
  const int f = tid;
  for (int e = 0; e < E_; ++e) {
    float acc = btar[f];
    const float* wr = Wtar + f * 128;
    #pragma unroll 4
    for (int k = 0; k < 128; ++k) acc = fmaf(wr[k], ohl[e * 128 + k], acc);
    float m = acc;
    #pragma unroll
    for (int off = 32; off; off >>= 1) m = fmaxf(m, __shfl_xor(m, off, 64));
    float ex = __expf(acc - m);
    float s = ex;
    #pragma unroll
    for (int off = 32; off; off >>= 1) s += __shfl_xor(s, off, 64);
    outp[((size_t)t * 8 + e) * 64 + f] = ex / s;
  }
  if (tid < 8) {
    int e = tid;
    float d0 = bdir[0], d1 = bdir[1], d2 = bdir[2];
    #pragma unroll 4
    for (int k = 0; k < 128; ++k) {
      float x = ohl[e * 128 + k];
      d0 = fmaf(Wdir[k], x, d0);
      d1 = fmaf(Wdir[128 + k], x, d1);
      d2 = fmaf(Wdir[256 + k], x, d2);
    }
    float m = fmaxf(d0, fmaxf(d1, d2));
    float x0 = __expf(d0 - m), x1 = __expf(d1 - m), x2 = __expf(d2 - m);
    float s = x0 + x1 + x2;
    float* dp = outp + (size_t)T_ * 8 * 64 + ((size_t)t * 8 + e) * 3;
    dp[0] = x0 / s; dp[1] = x1 / s; dp[2] = x2 / s;
  }
}

extern "C" void kernel_launch(void* const* d_in, const int* in_sizes, int n_in,
                              void* d_out, int out_size, void* d_ws, size_t ws_size,
                              hipStream_t stream) {
  (void)in_sizes; (void)n_in; (void)out_size; (void)ws_size;
  const float* feat   = (const float*)d_in[0];
  const float* pre_h0 = (const float*)d_in[1];
  const float* pre_c0 = (const float*)d_in[2];
  const float* out_h0 = (const float*)d_in[3];
  const float* out_c0 = (const float*)d_in[4];
  const float* Wih_p0 = (const float*)d_in[5];
  const float* Whh_p0 = (const float*)d_in[6];
  const float* b_p0   = (const float*)d_in[7];
  const float* Wih_p1 = (const float*)d_in[8];
  const float* Whh_p1 = (const float*)d_in[9];
  const float* b_p1   = (const float*)d_in[10];
  const float* Wfc    = (const float*)d_in[11];
  const float* bfc    = (const float*)d_in[12];
  const float* Wih_c0 = (const float*)d_in[13];
  const float* Whh_c0 = (const float*)d_in[14];
  const float* b_c0   = (const float*)d_in[15];
  const float* Wih_c1 = (const float*)d_in[16];
  const float* Whh_c1 = (const float*)d_in[17];
  const float* b_c1   = (const float*)d_in[18];
  const float* Wih_o  = (const float*)d_in[19];
  const float* Whh_o  = (const float*)d_in[20];
  const float* b_o    = (const float*)d_in[21];
  const float* Wtar   = (const float*)d_in[22];
  const float* btar   = (const float*)d_in[23];
  const float* Wdir   = (const float*)d_in[24];
  const float* bdir   = (const float*)d_in[25];
  float* outp = (float*)d_out;

  float* ws = (float*)d_ws;
  size_t off = 0;
  float* opre1    = ws + off; off += (size_t)T_ * 512;
  float* oh_g     = ws + off; off += (size_t)T_ * E_ * 128;
  float* wt_p0    = ws + off; off += (size_t)448 * 1024;
  float* wt_p1    = ws + off; off += (size_t)512 * 1024;
  float* wt_c0    = ws + off; off += (size_t)256 * 512;
  float* wt_c1    = ws + off; off += (size_t)256 * 512;
  float* wt_o1    = ws + off; off += (size_t)256 * 512;
  float* wt_o2    = ws + off; off += (size_t)192 * 512;
  __hip_bfloat16* opre2 = (__hip_bfloat16*)(ws + off);
  off += (size_t)T_ * E_ * 512 / 2;
  float* h1all  = ws + off; off += (size_t)T_ * 2048;
  float* h0ring = ws + off; off += (size_t)8 * 2048;
  float* h1ring = ws + off; off += (size_t)8 * 2048;
  int* flags    = (int*)(ws + off);          // flagsA + flagsB + flagC
  int* flagsA   = flags;
  int* flagsB   = flags + (size_t)64 * 16 * 32;
  int* flagC    = flags + (size_t)2 * 64 * 16 * 32;   // 512 slots x 32 stride

  initK<<<dim3(1024), dim3(256), 0, stream>>>(
      Wih_p0, Whh_p0, Wih_p1, Whh_p1, Wih_c0, Whh_c0, Wih_c1, Whh_c1, Wih_o,
      wt_p0, wt_p1, wt_c0, wt_c1, wt_o1, wt_o2, flags);
  opre2K<<<dim3(T_), dim3(256), 0, stream>>>(feat, wt_o2, opre2);
  megaK<<<dim3(32 + 8 + NCON), dim3(256), 0, stream>>>(
      feat, pre_h0, pre_c0, wt_p0, wt_p1, b_p0, b_p1,
      h0ring, h1ring, h1all, flagsA, flagsB,
      Wfc, bfc, wt_c0, wt_c1, b_c0, b_c1, wt_o1, b_o, opre1, flagC,
      opre2, Whh_o, out_h0, out_c0, oh_g);
  phaseD<<<dim3(T_), dim3(64), 0, stream>>>(oh_g, Wtar, btar, Wdir, bdir, outp);
}